// Round 4
// baseline (258.855 us; speedup 1.0000x reference)
//
#include <hip/hip_runtime.h>
#include <hip/hip_bf16.h>

#define N_ATOMS 50000
#define N_EDGES 800000
#define DEG 16
#define N_MOL 1000
#define NA 23
#define NB 7
#define O0 32
#define O1 12
#define O2 8
#define OZ 21          // folded output width: w0f(7) | w1f(7) | w2f(7)
#define NT 2           // N-tiles of 16
#define NPW 4          // nodes per wave in k2
#define MAXD 64        // padded CSR row (Poisson(16); P(deg>64) ~ 1e-21)
#define VFRAG_N 896    // 14 fragments * 64 lanes, short8 each (14336 B)

typedef __attribute__((ext_vector_type(8))) short short8;
typedef __attribute__((ext_vector_type(4))) float floatx4;

__device__ __forceinline__ unsigned short bfbits(float f) {  // f32 -> bf16 RNE
    unsigned u = __float_as_uint(f);
    u += 0x7FFFu + ((u >> 16) & 1u);
    return (unsigned short)(u >> 16);
}
__device__ __forceinline__ float bf_lo(unsigned u) { return __uint_as_float(u << 16); }
__device__ __forceinline__ float bf_hi(unsigned u) { return __uint_as_float(u & 0xFFFF0000u); }
__device__ __forceinline__ float wred4(float v) {  // sum over the 4 quads
    v += __shfl_xor(v, 16, 64); v += __shfl_xor(v, 32, 64); return v;
}

// ---------------- K_zero: deg + out (must precede k_prep's CSR atomics) -----
__global__ void k_zero(int* __restrict__ deg, float* __restrict__ out) {
    int idx = blockIdx.x * 256 + threadIdx.x;
    if (idx < N_ATOMS) deg[idx] = 0;
    if (idx < N_MOL) out[idx] = 0.0f;
}

// ---------------- K_prep: Vfrag(W1*W2 folded) + x_bf + pos4 + ea_bf + CSR ---
__global__ void k_prep(const float* __restrict__ W1_0, const float* __restrict__ W1_1,
                       const float* __restrict__ W1_2,
                       const float* __restrict__ W2_0, const float* __restrict__ W2_1,
                       const float* __restrict__ W2_2,
                       const float* __restrict__ x, const float* __restrict__ pos,
                       const float* __restrict__ ea, const int* __restrict__ edge_src,
                       unsigned short* __restrict__ Vfrag,
                       unsigned short* __restrict__ x_bf, float4* __restrict__ pos4,
                       unsigned short* __restrict__ ea_bf,
                       int* __restrict__ deg, int* __restrict__ csr) {
    int idx = blockIdx.x * 256 + threadIdx.x;
    if (idx < VFRAG_N * 8) {
        int j    = idx & 7;
        int lane = (idx >> 3) & 63;
        int st   = idx >> 9;           // 0..13 = s*NT+t
        int s = st >> 1, t = st & 1;
        int a = (lane >> 4) * 8 + j, o = t * 16 + (lane & 15);
        float val = 0.f;
        if (a < NA && o < OZ) {
            const float n1 = 0.07881104062391006f;   // 1/sqrt(23*7)
            const float q  = 0.25f;                  // inv_sqrt_deg (deg==16)
            float acc = 0.f;
            if (o < 7) {
                const float c0 = 0.06681531047810609f;   // 1/sqrt(32*7)
                const float* w1 = W1_0 + (a * NB + s) * O0;
                for (int k = 0; k < O0; k++) acc += w1[k] * W2_0[k * NB + o];
                val = acc * (n1 * c0 * q);
            } else if (o < 14) {
                const float c1 = 0.06299407883487121f;   // 1/(sqrt(12*7)*sqrt(3))
                const float* w1 = W1_1 + (a * NB + s) * O1;
                for (int k = 0; k < O1; k++) acc += w1[k] * W2_1[k * NB + (o - 7)];
                val = acc * (n1 * c1 * q);
            } else {
                const float c2 = 0.05976143046671968f;   // 1/(sqrt(8*7)*sqrt(5))
                const float* w1 = W1_2 + (a * NB + s) * O2;
                for (int k = 0; k < O2; k++) acc += w1[k] * W2_2[k * NB + (o - 14)];
                val = acc * (n1 * c2 * q);
            }
        }
        Vfrag[idx] = bfbits(val);
    }
    if (idx < N_ATOMS) {
        float4 p; p.x = pos[idx * 3 + 0]; p.y = pos[idx * 3 + 1];
        p.z = pos[idx * 3 + 2]; p.w = 0.f;
        pos4[idx] = p;
    }
    if (idx < N_ATOMS * 32) {
        int n = idx >> 5, a = idx & 31;
        x_bf[idx] = bfbits((a < NA) ? x[n * NA + a] : 0.f);
    }
    if (idx < N_EDGES) {
        // pack edge_attr row to bf16x8 (one 16B line)
        const float* p = ea + (size_t)idx * NB;
        union { unsigned short us[8]; uint4 q; } t;
        #pragma unroll
        for (int b = 0; b < NB; b++) t.us[b] = bfbits(p[b]);
        t.us[7] = 0;
        *(uint4*)(ea_bf + (size_t)idx * 8) = t.q;
        // CSR-by-src (padded): slot = atomic rank within src's list
        int s = edge_src[idx];
        int c = atomicAdd(&deg[s], 1);
        if (c < MAXD) csr[(size_t)s * MAXD + c] = idx;
    }
}

// ---------------- K2: MFMA GEMM + fused outgoing-edge phase ------------------
// Per node n: compute z (63 f32) -> LDS broadcast -> each lane handles one
// outgoing edge (src==n): e = sum_b ea[b]*(z0 + sum_m h_m*z_m + h8*c8),
// scatter to evals[eid].
__global__ __launch_bounds__(256, 5) void k2_s(const float4* __restrict__ pos4,
        const unsigned short* __restrict__ x_bf, const int* __restrict__ edge_src,
        const unsigned short* __restrict__ Vfrag, const unsigned short* __restrict__ ea_bf,
        const int* __restrict__ deg, const int* __restrict__ csr,
        float* __restrict__ evals) {
    __shared__ short8 wfrag[VFRAG_N];          // 14336 B, shared by 4 waves
    __shared__ float hbuf[4][16][8];           // 2 KB
    __shared__ float zl[4][64];                // 1 KB: z broadcast per wave
    const int tid  = threadIdx.x;
    const int wid  = tid >> 6;
    const int lane = tid & 63;
    const int lcol = lane & 15;
    const int quad = lane >> 4;

    {   // cooperative stage of the prebuilt folded-weight fragments
        uint4* dst = (uint4*)wfrag;
        const uint4* src4 = (const uint4*)Vfrag;
        for (int i = tid; i < VFRAG_N; i += 256) dst[i] = src4[i];
    }
    __syncthreads();

    const int wgid = __builtin_amdgcn_readfirstlane(blockIdx.x * 4 + wid);
    const int base = wgid * NPW;
    if (base >= N_ATOMS) return;

    float (*hb)[8] = hbuf[wid];
    float* zw = &zl[wid][0];
    const float s3 = 1.7320508075688772f, s15 = 3.872983346207417f;
    const float s5h = 1.118033988749895f, s15h = 1.9364916731037085f;

    // ---- outgoing-edge lists (coalesced) + first-node edge gathers ----
    int eidv[NPW], cnts[NPW];
    #pragma unroll
    for (int ii = 0; ii < NPW; ii++) {
        eidv[ii] = csr[(size_t)(base + ii) * MAXD + lane];
        cnts[ii] = deg[base + ii];
    }
    int ecur = (lane < cnts[0]) ? eidv[0] : 0;
    uint4 eaq = *(const uint4*)(ea_bf + (size_t)ecur * 8);
    float4 pD = pos4[ecur >> 4];

    auto clampn = [&](int i) { int nn = base + i; return nn < N_ATOMS ? nn : N_ATOMS - 1; };
    int s0v = edge_src[clampn(0) * DEG + lcol];
    int s1v = edge_src[clampn(1) * DEG + lcol];
    uint4 xu0 = *(const uint4*)(x_bf + s0v * 32 + quad * 8);
    float4 pp0 = pos4[s0v];
    float e0v[NB];
    {
        uint4 eu = *(const uint4*)(ea_bf + ((size_t)clampn(0) * DEG + lcol) * 8);
        e0v[0] = bf_lo(eu.x); e0v[1] = bf_hi(eu.x); e0v[2] = bf_lo(eu.y);
        e0v[3] = bf_hi(eu.y); e0v[4] = bf_lo(eu.z); e0v[5] = bf_hi(eu.z);
        e0v[6] = bf_lo(eu.w);
    }

    #pragma unroll 1
    for (int i = 0; i < NPW; i++) {
        const int n = base + i;
        if (n >= N_ATOMS) break;
        // ---- prefetch next node's incoming-edge data ----
        int s2v = edge_src[clampn(i + 2 < NPW ? i + 2 : i) * DEG + lcol];
        uint4 xu1 = *(const uint4*)(x_bf + s1v * 32 + quad * 8);
        float4 pp1 = pos4[s1v];
        float e1v[NB];
        {
            uint4 eu = *(const uint4*)(ea_bf + ((size_t)clampn(i + 1 < NPW ? i + 1 : i) * DEG + lcol) * 8);
            e1v[0] = bf_lo(eu.x); e1v[1] = bf_hi(eu.x); e1v[2] = bf_lo(eu.y);
            e1v[3] = bf_hi(eu.y); e1v[4] = bf_lo(eu.z); e1v[5] = bf_hi(eu.z);
            e1v[6] = bf_lo(eu.w);
        }
        // ---- prefetch next node's OUTGOING edge data (hidden under MFMA) ----
        int enext = 0;
        if (i + 1 < NPW) enext = (lane < cnts[i + 1]) ? eidv[i + 1] : 0;
        uint4 eaq1 = *(const uint4*)(ea_bf + (size_t)enext * 8);
        float4 pD1 = pos4[enext >> 4];

        // ---- unpack this node's x slice ----
        float xf[8];
        xf[0] = bf_lo(xu0.x); xf[1] = bf_hi(xu0.x);
        xf[2] = bf_lo(xu0.y); xf[3] = bf_hi(xu0.y);
        xf[4] = bf_lo(xu0.z); xf[5] = bf_hi(xu0.z);
        xf[6] = bf_lo(xu0.w); xf[7] = bf_hi(xu0.w);

        // ---- h-factors for node n's incoming edges (lanes 0..15) ----
        const float4 pd = pos4[n];          // uniform; also reused as src-pos below
        if (lane < 16) {
            const float vx = pp0.x - pd.x, vy = pp0.y - pd.y, vz = pp0.z - pd.z;
            hb[lane][0] = s3 * vx;  hb[lane][1] = s3 * vy;  hb[lane][2] = s3 * vz;
            hb[lane][3] = s15 * vx * vy;
            hb[lane][4] = s15 * vy * vz;
            hb[lane][5] = s5h * (2.f * vz * vz - vx * vx - vy * vy);
            hb[lane][6] = s15 * vx * vz;
            hb[lane][7] = s15h * (vx * vx - vy * vy);
        }
        // ---- MFMA: 7 K-steps x 2 N-tiles (folded weights) ----
        floatx4 acc0 = {0.f,0.f,0.f,0.f}, acc1 = {0.f,0.f,0.f,0.f};
        #pragma unroll
        for (int s = 0; s < 7; s++) {
            const float eb = e0v[s];
            union { short8 v; unsigned u[4]; } af;
            #pragma unroll
            for (int j = 0; j < 8; j += 2) {
                float2 pr; pr.x = xf[j] * eb; pr.y = xf[j + 1] * eb;
                __hip_bfloat162 bb = __float22bfloat162_rn(pr);
                af.u[j >> 1] = *(unsigned*)&bb;
            }
            acc0 = __builtin_amdgcn_mfma_f32_16x16x32_bf16(af.v, wfrag[(s*NT+0)*64 + lane], acc0, 0, 0, 0);
            acc1 = __builtin_amdgcn_mfma_f32_16x16x32_bf16(af.v, wfrag[(s*NT+1)*64 + lane], acc1, 0, 0, 0);
        }
        // ---- epilogue: z-row (63 f32) into LDS ----
        float4 hA[4], hB[4];
        #pragma unroll
        for (int r = 0; r < 4; r++) {
            int e = quad * 4 + r;
            hA[r] = *(const float4*)&hb[e][0];   // sh1 x,y,z | sh2 m0
            hB[r] = *(const float4*)&hb[e][4];   // sh2 m1..m4
        }
        const bool useA = (lcol >= 14);          // z2 source: acc0 cols 14,15 else acc1 cols 0..4
        float v0 = acc0[0] + acc0[1] + acc0[2] + acc0[3];
        float u0 = 0.f, u1 = 0.f, u2 = 0.f;
        float t0 = 0.f, t1 = 0.f, t2 = 0.f, t3 = 0.f, t4 = 0.f;
        #pragma unroll
        for (int r = 0; r < 4; r++) {
            float m0 = acc0[r], m1 = acc1[r];
            u0 += m0 * hA[r].x; u1 += m0 * hA[r].y; u2 += m0 * hA[r].z;
            float mz = useA ? m0 : m1;
            t0 += mz * hA[r].w; t1 += mz * hB[r].x; t2 += mz * hB[r].y;
            t3 += mz * hB[r].z; t4 += mz * hB[r].w;
        }
        v0 = wred4(v0);
        u0 = wred4(u0); u1 = wred4(u1); u2 = wred4(u2);
        t0 = wred4(t0); t1 = wred4(t1); t2 = wred4(t2); t3 = wred4(t3); t4 = wred4(t4);
        if (quad == 0) {
            if (lcol < 7) zw[lcol * 8] = v0;                        // c=0
            else if (lcol < 14) {                                   // c=1..3 (sh1)
                int b = lcol - 7;
                zw[b * 8 + 1] = u0; zw[b * 8 + 2] = u1; zw[b * 8 + 3] = u2;
            }
            if (lcol >= 14 || lcol < 5) {                           // c=4..8 (sh2)
                int b = useA ? (lcol - 14) : (lcol + 2);
                zw[b * 8 + 4] = t0; zw[b * 8 + 5] = t1; zw[b * 8 + 6] = t2;
                zw[b * 8 + 7] = t3; zw[56 + b] = t4;
            }
        }
        // ---- fused outgoing-edge phase (same-wave LDS write->read is in-order) ----
        {
            float eaf[NB];
            eaf[0] = bf_lo(eaq.x); eaf[1] = bf_hi(eaq.x); eaf[2] = bf_lo(eaq.y);
            eaf[3] = bf_hi(eaq.y); eaf[4] = bf_lo(eaq.z); eaf[5] = bf_hi(eaq.z);
            eaf[6] = bf_lo(eaq.w);
            // vec = pos[src=n] - pos[dst]
            const float vx = pd.x - pD.x, vy = pd.y - pD.y, vz = pd.z - pD.z;
            const float hh1 = s3 * vx, hh2 = s3 * vy, hh3 = s3 * vz;
            const float hh4 = s15 * vx * vy, hh5 = s15 * vy * vz;
            const float hh6 = s5h * (2.f * vz * vz - vx * vx - vy * vy);
            const float hh7 = s15 * vx * vz, hh8 = s15h * (vx * vx - vy * vy);
            float acc = 0.f;
            #pragma unroll
            for (int b = 0; b < NB; b++) {
                float4 zA = *(const float4*)&zw[b * 8];
                float4 zB = *(const float4*)&zw[b * 8 + 4];
                float c8  = zw[56 + b];
                float t = zA.x + hh1 * zA.y + hh2 * zA.z + hh3 * zA.w
                        + hh4 * zB.x + hh5 * zB.y + hh6 * zB.z + hh7 * zB.w
                        + hh8 * c8;
                acc += eaf[b] * t;
            }
            if (lane < cnts[i]) evals[eidv[i]] = acc;
        }
        // ---- rotate pipelines ----
        s0v = s1v; s1v = s2v;
        xu0 = xu1; pp0 = pp1;
        #pragma unroll
        for (int b = 0; b < NB; b++) e0v[b] = e1v[b];
        eaq = eaq1; pD = pD1;
    }
}

// ---------------- K3: coalesced per-dst reduction of evals -------------------
__global__ __launch_bounds__(256, 8) void k3_reduce(const float* __restrict__ evals,
                                                    float* __restrict__ out) {
    const int idx = blockIdx.x * 256 + threadIdx.x;   // edge id (dst-major)
    float v = evals[idx];
    v += __shfl_xor(v, 1, 64);
    v += __shfl_xor(v, 2, 64);
    v += __shfl_xor(v, 4, 64);
    v += __shfl_xor(v, 8, 64);
    if ((threadIdx.x & 15) == 0)
        atomicAdd(out + (idx >> 4) / 50, v * 0.035355339059327376f);  // 0.25/sqrt(50)
}

extern "C" void kernel_launch(void* const* d_in, const int* in_sizes, int n_in,
                              void* d_out, int out_size, void* d_ws, size_t ws_size,
                              hipStream_t stream) {
    const float* pos  = (const float*)d_in[0];
    const float* x    = (const float*)d_in[1];
    const float* ea   = (const float*)d_in[2];
    const float* W1_0 = (const float*)d_in[3];
    const float* W1_1 = (const float*)d_in[4];
    const float* W1_2 = (const float*)d_in[5];
    const float* W2_0 = (const float*)d_in[6];
    const float* W2_1 = (const float*)d_in[7];
    const float* W2_2 = (const float*)d_in[8];
    const int*   esrc = (const int*)d_in[9];
    float* out = (float*)d_out;

    char* ws = (char*)d_ws;
    unsigned short* Vfrag = (unsigned short*)ws;                          // 32 KB
    unsigned short* ea_bf = (unsigned short*)(ws + 32768);                // 12.8 MB
    int*            csr   = (int*)(ws + 32768 + 12800000);                // 12.8 MB
    float*          evals = (float*)(ws + 32768 + 25600000);              // 3.2 MB
    unsigned short* x_bf  = (unsigned short*)(ws + 32768 + 28800000);     // 3.2 MB
    float4*         pos4  = (float4*)(ws + 32768 + 32000000);             // 800 KB
    int*            deg   = (int*)(ws + 32768 + 32800000);                // 200 KB

    hipLaunchKernelGGL(k_zero, dim3((N_ATOMS + 255) / 256), dim3(256), 0, stream,
                       deg, out);
    hipLaunchKernelGGL(k_prep, dim3((N_ATOMS * 32 + 255) / 256), dim3(256), 0, stream,
                       W1_0, W1_1, W1_2, W2_0, W2_1, W2_2, x, pos, ea, esrc,
                       Vfrag, x_bf, pos4, ea_bf, deg, csr);
    hipLaunchKernelGGL(k2_s, dim3(N_ATOMS / NPW / 4), dim3(256), 0, stream,
                       pos4, x_bf, esrc, Vfrag, ea_bf, deg, csr, evals);
    hipLaunchKernelGGL(k3_reduce, dim3(N_EDGES / 256), dim3(256), 0, stream,
                       evals, out);
}